// Round 10
// baseline (240.367 us; speedup 1.0000x reference)
//
#include <hip/hip_runtime.h>
#include <hip/hip_bf16.h>

// ---------------- problem constants ----------------
#define BATCH   4
#define SEQ     2048
#define DMODEL  512
#define NHEADS  8
#define HEADDIM 64
#define MTOT    (BATCH*SEQ)      // 8192 rows
#define NX      (MTOT*DMODEL)    // 4194304 x elements
#define NW      (DMODEL*DMODEL)  // 262144 weight elements
#define QTILE   128
#define KTILE   64
#define NKT     (SEQ/KTILE)      // 32

#define LOG2E   1.4426950408889634f
#define SCL2    0.18033688011112042f      // 0.125 * log2e
#define SHIFT   14.426950408889634f       // overflow headroom shift
#define BIGL2   1.4426950408889634e9f
// ---------------------------------------------------

typedef unsigned short u16;
typedef __bf16 bf16x8 __attribute__((ext_vector_type(8)));
typedef float  f32x4  __attribute__((ext_vector_type(4)));
typedef float  f32x16 __attribute__((ext_vector_type(16)));
typedef unsigned short u16x4 __attribute__((ext_vector_type(4)));
typedef unsigned u32x2 __attribute__((ext_vector_type(2)));

#define MFMA(a,b,c)   __builtin_amdgcn_mfma_f32_16x16x32_bf16(a,b,c,0,0,0)
#define MFMA32(a,b,c) __builtin_amdgcn_mfma_f32_32x32x16_bf16(a,b,c,0,0,0)

__device__ __forceinline__ u16 f2bf(float f) {
    unsigned u = __float_as_uint(f);
    u += 0x7FFFu + ((u >> 16) & 1u);   // RNE
    return (u16)(u >> 16);
}
__device__ __forceinline__ unsigned pk_bf16(float a, float b) {
    union { __hip_bfloat162 h; unsigned u; } cv;
    cv.h = __float22bfloat162_rn(make_float2(a, b));
    return cv.u;
}
__device__ __forceinline__ void gll16(const void* g, void* l) {
    __builtin_amdgcn_global_load_lds((const __attribute__((address_space(1))) void*)g,
                                     (__attribute__((address_space(3))) void*)l, 16, 0, 0);
}
__device__ __forceinline__ void gll4(const void* g, void* l) {
    __builtin_amdgcn_global_load_lds((const __attribute__((address_space(1))) void*)g,
                                     (__attribute__((address_space(3))) void*)l, 4, 0, 0);
}

// ---------------- kernel 0: fp32 -> bf16 converts + rope cos/sin table ----------------
#define NCVT4 ((NX + 4*NW)/4)    // 1310720 float4 groups
__global__ __launch_bounds__(256) void cvt_rope_kernel(
    const float* __restrict__ x,
    const float* __restrict__ wq, const float* __restrict__ wk,
    const float* __restrict__ wv, const float* __restrict__ wo,
    u16* __restrict__ xbf,
    u16* __restrict__ wqbf, u16* __restrict__ wkbf,
    u16* __restrict__ wvbf, u16* __restrict__ wobf,
    float2* __restrict__ cst)
{
    int i4 = blockIdx.x * 256 + threadIdx.x;
    if (i4 < NCVT4) {
        int i = i4 * 4;
        const float* s; u16* d; int o;
        if (i < NX) { s = x; d = xbf; o = i; }
        else {
            int j = i - NX;
            int r = j >> 18;            // NW = 2^18
            o = j & (NW - 1);
            s = (r == 0) ? wq : (r == 1) ? wk : (r == 2) ? wv : wo;
            d = (r == 0) ? wqbf : (r == 1) ? wkbf : (r == 2) ? wvbf : wobf;
        }
        float4 v = *(const float4*)(s + o);
        u16x4 u = { f2bf(v.x), f2bf(v.y), f2bf(v.z), f2bf(v.w) };
        *(u16x4*)(d + o) = u;
    } else {
        int r = i4 - NCVT4;             // [0, 16384)
        if (r < SEQ * 32 / 4) {
            int idx = r * 4;
            int s  = idx >> 5;
            int p0 = idx & 31;
#pragma unroll
            for (int t = 0; t < 4; ++t) {
                int p = p0 + t;
                float inv = __expf(-0.5756462732485115f * (float)(p & 15));
                float ang = (float)s * inv;
                cst[idx + t] = make_float2(cosf(ang), sinf(ang));
            }
        }
    }
}

// ---------------- kernel 1: fused QKV projection + RoPE (round-9, verified) ----------------
#define TP 136   // LDS tile row stride (u16 elems)
__global__ __launch_bounds__(256) void qkv_kernel(
    const u16* __restrict__ x,
    const u16* __restrict__ Wq, const float* __restrict__ bq,
    const u16* __restrict__ Wk, const float* __restrict__ bk,
    const u16* __restrict__ Wv, const float* __restrict__ bv,
    const float* __restrict__ cstf,
    u16* __restrict__ qws, u16* __restrict__ kws, u16* __restrict__ vtws)
{
    __shared__ alignas(16) u16 smem[128 * TP];
    u16* As = smem;
    u16* Bs = smem + 8192;

    const int m0 = blockIdx.x * 128;
    const int n0 = blockIdx.y * 128;
    const int tid  = threadIdx.x;
    const int w    = tid >> 6;
    const int lane = tid & 63;
    const int quad = lane >> 4;
    const int l16  = lane & 15;
    const int wm = w & 1, wn = w >> 1;

    const int sec = n0 >> 9;
    const int oc0 = n0 & 511;
    const u16*   Wm = (sec == 0) ? Wq : (sec == 1 ? Wk : Wv);
    const float* bb = (sec == 0) ? bq : (sec == 1 ? bk : bv);

    const int xb = (sec < 2) ? wn : wm;
    const int wb = (sec < 2) ? wm : wn;

    f32x4 acc[4][4] = {};

    for (int kb = 0; kb < 8; ++kb) {
#pragma unroll
        for (int it = 0; it < 4; ++it) {
            const int s   = it * 256 + tid;
            const int row = s >> 3;
            const int cb  = s & 7;
            const int gcol = kb * 64 + (((cb ^ (row & 7))) << 3);
            gll16(x  + (m0  + row) * 512 + gcol, &As[s * 8]);
            gll16(Wm + (oc0 + row) * 512 + gcol, &Bs[s * 8]);
        }
        __syncthreads();

#pragma unroll
        for (int ks = 0; ks < 2; ++ks) {
            bf16x8 xf[4], wf[4];
#pragma unroll
            for (int t = 0; t < 4; ++t) {
                const int xrow = xb * 64 + t * 16 + l16;
                const int wrow = wb * 64 + t * 16 + l16;
                xf[t] = *(const bf16x8*)&As[xrow * 64 + (((ks * 4 + quad) ^ (xrow & 7)) << 3)];
                wf[t] = *(const bf16x8*)&Bs[wrow * 64 + (((ks * 4 + quad) ^ (wrow & 7)) << 3)];
            }
            if (sec < 2) {
#pragma unroll
                for (int tm = 0; tm < 4; ++tm)
#pragma unroll
                    for (int tn = 0; tn < 4; ++tn)
                        acc[tm][tn] = MFMA(wf[tm], xf[tn], acc[tm][tn]);
            } else {
#pragma unroll
                for (int tm = 0; tm < 4; ++tm)
#pragma unroll
                    for (int tn = 0; tn < 4; ++tn)
                        acc[tm][tn] = MFMA(xf[tm], wf[tn], acc[tm][tn]);
            }
        }
        __syncthreads();
    }

    if (sec < 2) {
#pragma unroll
        for (int tm = 0; tm < 4; ++tm) {
            const int dls = wm * 64 + tm * 16 + quad * 4;
            const float4 bv4 = *(const float4*)&bb[oc0 + dls];
            const int pbase = ((oc0 + dls) & 63) >> 1;
#pragma unroll
            for (int tn = 0; tn < 4; ++tn) {
                const int sl = wn * 64 + tn * 16 + l16;
                const int sg = (m0 + sl) & 2047;
                const float4 cs = *(const float4*)&cstf[sg * 64 + pbase * 2];
                const float v0 = acc[tm][tn][0] + bv4.x;
                const float v1 = acc[tm][tn][1] + bv4.y;
                const float v2 = acc[tm][tn][2] + bv4.z;
                const float v3 = acc[tm][tn][3] + bv4.w;
                const float r0 = v0 * cs.x - v1 * cs.y;
                const float r1 = v1 * cs.x + v0 * cs.y;
                const float r2 = v2 * cs.z - v3 * cs.w;
                const float r3 = v3 * cs.z + v2 * cs.w;
                u32x2 pv = { pk_bf16(r0, r1), pk_bf16(r2, r3) };
                *(u32x2*)&smem[sl * TP + dls] = pv;
            }
        }
        __syncthreads();
        u16* dst0 = (sec == 0) ? qws : kws;
#pragma unroll
        for (int i = 0; i < 8; ++i) {
            const int c   = i * 256 + tid;
            const int sl  = c >> 4;
            const int d8  = (c & 15) * 8;
            const int gcol = oc0 + d8;
            const int hh  = gcol >> 6;
            const int dh  = gcol & 63;
            const int sgl = m0 + sl;
            const int bi  = sgl >> 11;
            const int s   = sgl & 2047;
            u16* dst = dst0 + (size_t)(bi * NHEADS + hh) * (SEQ * HEADDIM)
                            + (size_t)s * HEADDIM + dh;
            *(bf16x8*)dst = *(const bf16x8*)&smem[sl * TP + d8];
        }
    } else {
#pragma unroll
        for (int tm = 0; tm < 4; ++tm) {
            const int row_l = wm * 64 + tm * 16 + quad * 4;
#pragma unroll
            for (int tn = 0; tn < 4; ++tn) {
                const int col_l = wn * 64 + tn * 16 + l16;
                const float bval = bb[oc0 + col_l];
                u32x2 pv = { pk_bf16(acc[tm][tn][0] + bval, acc[tm][tn][1] + bval),
                             pk_bf16(acc[tm][tn][2] + bval, acc[tm][tn][3] + bval) };
                *(u32x2*)&smem[col_l * TP + row_l] = pv;
            }
        }
        __syncthreads();
        const int bi  = m0 >> 11;
        const int sgb = m0 & 2047;
#pragma unroll
        for (int i = 0; i < 8; ++i) {
            const int c    = i * 256 + tid;
            const int col  = c >> 4;
            const int sc8  = (c & 15) * 8;
            const int gcol = oc0 + col;
            const int hh   = gcol >> 6;
            const int d    = gcol & 63;
            u16* dst = vtws + (size_t)(bi * NHEADS + hh) * (SEQ * HEADDIM)
                            + (size_t)d * SEQ + sgb + sc8;
            *(bf16x8*)dst = *(const bf16x8*)&smem[col * TP + sc8];
        }
    }
}

// ---------------- kernel 2: flash attention, 32x32 MFMA + k-split wave pairs ----------------
// grid (16, 32), block 512 = 8 waves: qg = w&3 (32 q-rows each), kh = w>>2 (32k half).
// Shift-softmax (no running max) => k-split partials are directly addable at the end.
// LDS carve: kbuf 16K | vbuf 16K | pls 8x(32x40 u16)=20K | bid/bmk 1K = 54272 B.
// pls row stride 40 u16 (80 B): h2-halves land on disjoint bank halves (conflict-free b16 w).
#define PLSTR 40
__global__ __launch_bounds__(512, 4) void attn_kernel(
    const u16* __restrict__ qws, const u16* __restrict__ kws,
    const u16* __restrict__ vtl,
    const int* __restrict__ vids, const float* __restrict__ mask,
    const float* __restrict__ u_same, const float* __restrict__ u_cross,
    u16* __restrict__ attn)
{
    __shared__ alignas(16) char smraw[54272];
    u16*   kbuf = (u16*)smraw;                       // [2][4096]
    u16*   vbuf = (u16*)(smraw + 16384);             // [2][4096]
    u16*   pls  = (u16*)(smraw + 32768);             // [8][32*PLSTR]
    int*   bidb = (int*)(smraw + 53248);             // [2][64]
    float* bmkb = (float*)(smraw + 53760);           // [2][64]

    const int bh = blockIdx.y;
    const int b  = bh >> 3;
    const int h  = bh & 7;
    const int q0 = blockIdx.x * QTILE;

    const int tid  = threadIdx.x;
    const int w    = tid >> 6;                // 0..7
    const int lane = tid & 63;
    const int l31  = lane & 31;
    const int h2   = lane >> 5;
    const int qg   = w & 3;
    const int kh   = w >> 2;
    const int qw   = q0 + qg * 32;

    const float us2 = u_same[h]  * LOG2E;
    const float uc2 = u_cross[h] * LOG2E;
    const size_t tb = (size_t)bh * (SEQ * HEADDIM);

    // Q A-frags (32x32x16): A[m=l31][k=h2*8+j], d-chunks c=0..3 -> 4 b128, kernel-lifetime
    bf16x8 aq[4];
#pragma unroll
    for (int c = 0; c < 4; ++c)
        aq[c] = *(const bf16x8*)(qws + tb + (qw + l31) * HEADDIM + c * 16 + h2 * 8);

    // variate ids for this lane's 16 C-rows: row = (r&3) + 8*(r>>2) + 4*h2
    int vq[16];
#pragma unroll
    for (int r = 0; r < 16; ++r)
        vq[r] = vids[b * SEQ + qw + (r & 3) + 8 * (r >> 2) + 4 * h2];

    float  li[16];
    f32x16 o0 = {}, o1 = {};
#pragma unroll
    for (int r = 0; r < 16; ++r) li[r] = 0.0f;

    u16* plsw = pls + w * (32 * PLSTR);

    // stage: full 64x64 K and V^T tiles, source-XOR swizzle swz(row)=(row&7)^(row>>3)
    const int srow = w * 8 + (lane >> 3);
    const int scb  = lane & 7;
    const int soff = ((scb ^ (srow & 7) ^ (srow >> 3)) << 3);
    auto stage = [&](int kt, int nb) {
        const int k0 = kt * KTILE;
        gll16(kws + tb + (size_t)(k0 + srow) * HEADDIM + soff, &kbuf[nb * 4096 + w * 512 + lane * 8]);
        gll16(vtl + tb + (size_t)srow * SEQ + k0 + soff,       &vbuf[nb * 4096 + w * 512 + lane * 8]);
        if (w == 0) {
            gll4(vids + b * SEQ + k0 + lane, &bidb[nb * 64]);
            gll4(mask + b * SEQ + k0 + lane, &bmkb[nb * 64]);
        }
    };

    const int krow = kh * 32 + l31;
    const int ksw  = (krow & 7) ^ (krow >> 3);

    auto body = [&](const int cur) {
        // ---- S = Q K^T over this wave's 32k half ----
        f32x16 s = {};
#pragma unroll
        for (int c = 0; c < 4; ++c) {
            const bf16x8 kb = *(const bf16x8*)&kbuf[cur * 4096 + krow * 64
                                                    + (((c * 2 + h2) ^ ksw) << 3)];
            s = MFMA32(aq[c], kb, s);
        }
        const int   kv  = bidb[cur * 64 + krow];
        const float mdl = fmaf(bmkb[cur * 64 + krow], BIGL2, -BIGL2 - SHIFT);
        const float as_ = us2 + mdl;
        const float ac_ = uc2 + mdl;

        // ---- p = exp2(s*SCL2 + sel), accumulate li, write P to per-wave pls ----
        float p[16];
#pragma unroll
        for (int r = 0; r < 16; ++r) {
            const float sel = (kv == vq[r]) ? as_ : ac_;
            p[r] = exp2f(fmaf(s[r], SCL2, sel));
            li[r] += p[r];
        }
#pragma unroll
        for (int r = 0; r < 16; r += 2) {
            const unsigned pk = pk_bf16(p[r], p[r + 1]);
            const int rowq = (r & 3) + 8 * (r >> 2) + 4 * h2;
            plsw[rowq * PLSTR + l31]       = (u16)pk;
            plsw[(rowq + 1) * PLSTR + l31] = (u16)(pk >> 16);
        }

        // ---- O += P @ V over this 32k half ----
        bf16x8 ap[2];
#pragma unroll
        for (int kc = 0; kc < 2; ++kc)
            ap[kc] = *(const bf16x8*)&plsw[l31 * PLSTR + kc * 16 + h2 * 8];
#pragma unroll
        for (int nt = 0; nt < 2; ++nt) {
            const int vrow = nt * 32 + l31;
            const int vsw  = (vrow & 7) ^ (vrow >> 3);
#pragma unroll
            for (int kc = 0; kc < 2; ++kc) {
                const bf16x8 vb = *(const bf16x8*)&vbuf[cur * 4096 + vrow * 64
                                        + (((kh * 4 + kc * 2 + h2) ^ vsw) << 3)];
                if (nt == 0) o0 = MFMA32(ap[kc], vb, o0);
                else         o1 = MFMA32(ap[kc], vb, o1);
            }
        }
    };

    stage(0, 0);
    for (int kt = 0; kt < NKT; kt += 2) {
        __syncthreads();                    // buffer0 staged; everyone done with buffer1
        stage(kt + 1, 1);
        body(0);
        __syncthreads();                    // buffer1 staged; everyone done with buffer0
        if (kt + 2 < NKT) stage(kt + 2, 0);
        body(1);
    }

    // ---- k-split combine through LDS (stride 49 f32: bank-permuting) ----
    __syncthreads();
    float* cmb = (float*)smraw;             // 4 qg x 64 lanes x 49 f32 = 50176 B
    float* cl  = cmb + qg * (64 * 49) + lane * 49;
    if (kh == 1) {
#pragma unroll
        for (int r = 0; r < 16; ++r) { cl[r] = o0[r]; cl[16 + r] = o1[r]; cl[32 + r] = li[r]; }
    }
    __syncthreads();
    if (kh == 0) {
#pragma unroll
        for (int r = 0; r < 16; ++r) { o0[r] += cl[r]; o1[r] += cl[16 + r]; li[r] += cl[32 + r]; }

        // li: reduce across the 32 cols (lanes within the h2 half), invert
#pragma unroll
        for (int r = 0; r < 16; ++r) {
            float v = li[r];
            v += __shfl_xor(v, 1);
            v += __shfl_xor(v, 2);
            v += __shfl_xor(v, 4);
            v += __shfl_xor(v, 8);
            v += __shfl_xor(v, 16);
            li[r] = 1.0f / v;
        }

        // store: row = qw + (r&3)+8*(r>>2)+4*h2, col = h*64 + nt*32 + l31
#pragma unroll
        for (int r = 0; r < 16; ++r) {
            const int rowq = qw + (r & 3) + 8 * (r >> 2) + 4 * h2;
            u16* dst = attn + (size_t)(b * SEQ + rowq) * DMODEL + h * HEADDIM + l31;
            dst[0]  = f2bf(o0[r] * li[r]);
            dst[32] = f2bf(o1[r] * li[r]);
        }
    }
}

// ---------------- kernel 3: output projection (round-9, verified) ----------------
__global__ __launch_bounds__(256) void proj_kernel(
    const u16* __restrict__ a, const u16* __restrict__ Wo,
    const float* __restrict__ bo, float* __restrict__ out)
{
    __shared__ alignas(16) u16 psm[132 * 64 * 2];
    u16* As = psm;
    u16* Bs = psm + 8192;
    float* Lp = (float*)psm;

    const int m0 = blockIdx.x * 128;
    const int n0 = blockIdx.y * 128;
    const int tid  = threadIdx.x;
    const int w    = tid >> 6;
    const int lane = tid & 63;
    const int quad = lane >> 4;
    const int l16  = lane & 15;
    const int wm = w & 1, wn = w >> 1;

    f32x4 acc[4][4] = {};

    for (int kb = 0; kb < 8; ++kb) {
#pragma unroll
        for (int it = 0; it < 4; ++it) {
            const int s   = it * 256 + tid;
            const int row = s >> 3;
            const int cb  = s & 7;
            const int gcol = kb * 64 + (((cb ^ (row & 7))) << 3);
            gll16(a  + (m0 + row) * 512 + gcol, &As[s * 8]);
            gll16(Wo + (n0 + row) * 512 + gcol, &Bs[s * 8]);
        }
        __syncthreads();

#pragma unroll
        for (int ks = 0; ks < 2; ++ks) {
            bf16x8 af[4], wf[4];
#pragma unroll
            for (int t = 0; t < 4; ++t) {
                const int arow = wn * 64 + t * 16 + l16;
                const int wrow = wm * 64 + t * 16 + l16;
                af[t] = *(const bf16x8*)&As[arow * 64 + (((ks * 4 + quad) ^ (arow & 7)) << 3)];
                wf[t] = *(const bf16x8*)&Bs[wrow * 64 + (((ks * 4 + quad) ^ (wrow & 7)) << 3)];
            }
#pragma unroll
            for (int tm = 0; tm < 4; ++tm)
#pragma unroll
                for (int tn = 0; tn < 4; ++tn)
                    acc[tm][tn] = MFMA(wf[tm], af[tn], acc[tm][tn]);
        }
        __syncthreads();
    }

#pragma unroll
    for (int hph = 0; hph < 2; ++hph) {
        if (wn == hph) {
#pragma unroll
            for (int tm = 0; tm < 4; ++tm) {
                const int dls = wm * 64 + tm * 16 + quad * 4;
                const float4 bv4 = *(const float4*)&bo[n0 + dls];
#pragma unroll
                for (int tn = 0; tn < 4; ++tn) {
                    const int s2 = tn * 16 + l16;
                    float4 v = { acc[tm][tn][0] + bv4.x, acc[tm][tn][1] + bv4.y,
                                 acc[tm][tn][2] + bv4.z, acc[tm][tn][3] + bv4.w };
                    *(float4*)&Lp[s2 * 132 + dls] = v;
                }
            }
        }
        __syncthreads();
#pragma unroll
        for (int i = 0; i < 8; ++i) {
            const int c  = i * 256 + tid;
            const int s2 = c >> 5;
            const int dq = (c & 31) * 4;
            float4 v = *(const float4*)&Lp[s2 * 132 + dq];
            *(float4*)&out[(size_t)(m0 + hph * 64 + s2) * 512 + n0 + dq] = v;
        }
        __syncthreads();
    }
}

// ---------------- launch ----------------
extern "C" void kernel_launch(void* const* d_in, const int* in_sizes, int n_in,
                              void* d_out, int out_size, void* d_ws, size_t ws_size,
                              hipStream_t stream) {
    const float* x    = (const float*)d_in[0];
    const int*   vids = (const int*)d_in[1];
    const float* mask = (const float*)d_in[2];
    const float* Wq = (const float*)d_in[3];
    const float* bq = (const float*)d_in[4];
    const float* Wk = (const float*)d_in[5];
    const float* bk = (const float*)d_in[6];
    const float* Wv = (const float*)d_in[7];
    const float* bv = (const float*)d_in[8];
    const float* Wo = (const float*)d_in[9];
    const float* bo = (const float*)d_in[10];
    const float* usame  = (const float*)d_in[11];
    const float* ucross = (const float*)d_in[12];
    float* out = (float*)d_out;

    u16* xbf  = (u16*)d_ws;                 // 8 MB; reused as attention output
    u16* wqbf = xbf + NX;                   // 512 KB each
    u16* wkbf = wqbf + NW;
    u16* wvbf = wkbf + NW;
    u16* wobf = wvbf + NW;
    float2* cst = (float2*)(wobf + NW);     // 512 KB
    u16* qws  = (u16*)(cst + SEQ * 32);     // 8 MB each
    u16* kws  = qws + (size_t)BATCH * NHEADS * SEQ * HEADDIM;
    u16* vtws = kws + (size_t)BATCH * NHEADS * SEQ * HEADDIM;
    u16* attn = xbf;

    cvt_rope_kernel<<<(NCVT4 + SEQ * 32 / 4 + 255) / 256, 256, 0, stream>>>(
        x, Wq, Wk, Wv, Wo, xbf, wqbf, wkbf, wvbf, wobf, cst);

    dim3 g1(MTOT / 128, 3 * DMODEL / 128);  // 64 x 12
    qkv_kernel<<<g1, 256, 0, stream>>>(xbf, wqbf, bq, wkbf, bk, wvbf, bv,
                                       (const float*)cst, qws, kws, vtws);

    dim3 g2(SEQ / QTILE, BATCH * NHEADS);   // 16 x 32
    attn_kernel<<<g2, 512, 0, stream>>>(qws, kws, vtws, vids, mask,
                                        usame, ucross, attn);

    dim3 g3(MTOT / 128, DMODEL / 128);      // 64 x 4
    proj_kernel<<<g3, 256, 0, stream>>>(attn, wobf, bo, out);
}